// Round 1
// 67.626 us; speedup vs baseline: 1.0801x; 1.0801x over previous
//
#include <hip/hip_runtime.h>

// SLayer: out[b,n] = sum_p exp(-sum_d (c[n,d]-x[b,p,d])^2 * s[n,d]^2) * mask[b,p]
// B=128, P=4096, N=64, D=2.  lane == n (N==64).
// v2: coalesced global->LDS staging (2 vector loads/wave) + wave-uniform
//     broadcast ds_read for compute. Kills the cold-HBM latency exposure of
//     48 serialized wave-uniform 16B global loads per wave (caches are flushed
//     every iteration by the harness's 268MB workspace poison fill).
// Exponent in Horner form:
//   -dist*log2e = (A0*x+B0)*x + (A1*y+B1)*y + E,  A=-w, B=2wc, E=-(w0c0^2+w1c1^2)
// -> 5 full-rate VALU + 1 v_exp_f32 per point per wave.

constexpr int B_ = 128;
constexpr int P_ = 4096;
constexpr int N_ = 64;
constexpr int CPB = 16;                // p-chunks (blocks) per batch item
constexpr int THREADS = 256;           // 4 waves
constexpr int WAVES = THREADS / 64;
constexpr int PTS_PER_BLOCK = P_ / CPB;            // 256
constexpr int PTS_PER_WAVE  = PTS_PER_BLOCK / WAVES; // 64

#if __has_builtin(__builtin_amdgcn_exp2f)
#define EXP2(x) __builtin_amdgcn_exp2f(x)
#else
#define EXP2(x) exp2f(x)
#endif

__global__ __launch_bounds__(THREADS, 8) void slayer_stage1(
    const float* __restrict__ batch,    // [B,P,2]
    const float* __restrict__ ndp,      // [B,P]
    const float* __restrict__ centers,  // [N,2]
    const float* __restrict__ sharp,    // [N,2]
    float* __restrict__ partial)        // [B,CPB,N]
{
    const int tid  = threadIdx.x;
    const int lane = tid & 63;          // lane == n
    const int wave = tid >> 6;
    const int b     = blockIdx.x / CPB;
    const int chunk = blockIdx.x % CPB;

    // per-wave staging buffers: batch slice (64 pts * 2 floats) + mask slice
    __shared__ float ldsA[WAVES][PTS_PER_WAVE * 2];  // [4][128] = 2 KB
    __shared__ float ldsM[WAVES][PTS_PER_WAVE];      // [4][64]  = 1 KB
    __shared__ float red[THREADS];

    const int p0 = chunk * PTS_PER_BLOCK + wave * PTS_PER_WAVE;

    // ---- coalesced stage: one float2/lane (batch) + one float/lane (mask) ----
    // lane i writes floats [2i,2i+1] of the wave's 128-float batch slice.
    const float2* gb = reinterpret_cast<const float2*>(batch + ((size_t)b * P_ + p0) * 2);
    reinterpret_cast<float2*>(ldsA[wave])[lane] = gb[lane];
    ldsM[wave][lane] = ndp[(size_t)b * P_ + p0 + lane];

    // per-n Horner constants (coalesced float2 loads, lane == n)
    const float2 cc = reinterpret_cast<const float2*>(centers)[lane];
    const float2 ss = reinterpret_cast<const float2*>(sharp)[lane];
    constexpr float LOG2E = 1.44269504088896340736f;
    const float w0 = ss.x * ss.x * LOG2E;
    const float w1 = ss.y * ss.y * LOG2E;
    const float A0 = -w0,           A1 = -w1;
    const float B0 = 2.f*w0*cc.x,   B1 = 2.f*w1*cc.y;
    const float E  = -(w0*cc.x*cc.x + w1*cc.y*cc.y);

    __syncthreads();   // staging visible (also orders cross-lane LDS writes)

    // ---- compute: wave-uniform broadcast reads from LDS ----
    const float4* bp = reinterpret_cast<const float4*>(&ldsA[wave][0]);
    const float4* mp = reinterpret_cast<const float4*>(&ldsM[wave][0]);

    float acc0 = 0.f, acc1 = 0.f;       // two chains for ILP
    #pragma unroll
    for (int i = 0; i < PTS_PER_WAVE / 4; ++i) {
        const float4 q01 = bp[2*i + 0];   // points p, p+1 (x,y,x,y)
        const float4 q23 = bp[2*i + 1];   // points p+2, p+3
        const float4 m   = mp[i];         // 4 masks

        float t0, t1, u;
        t0 = fmaf(A0, q01.x, B0); t1 = fmaf(A1, q01.y, B1);
        u  = fmaf(t0, q01.x, E);  u  = fmaf(t1, q01.y, u);
        acc0 = fmaf(EXP2(u), m.x, acc0);

        t0 = fmaf(A0, q01.z, B0); t1 = fmaf(A1, q01.w, B1);
        u  = fmaf(t0, q01.z, E);  u  = fmaf(t1, q01.w, u);
        acc1 = fmaf(EXP2(u), m.y, acc1);

        t0 = fmaf(A0, q23.x, B0); t1 = fmaf(A1, q23.y, B1);
        u  = fmaf(t0, q23.x, E);  u  = fmaf(t1, q23.y, u);
        acc0 = fmaf(EXP2(u), m.z, acc0);

        t0 = fmaf(A0, q23.z, B0); t1 = fmaf(A1, q23.w, B1);
        u  = fmaf(t0, q23.z, E);  u  = fmaf(t1, q23.w, u);
        acc1 = fmaf(EXP2(u), m.w, acc1);
    }

    // combine the block's 4 waves; lane l of every wave holds n==l
    red[tid] = acc0 + acc1;
    __syncthreads();
    if (tid < 64) {
        partial[(size_t)blockIdx.x * N_ + tid] =
            red[tid] + red[tid + 64] + red[tid + 128] + red[tid + 192];
    }
}

__global__ __launch_bounds__(256) void slayer_stage2(
    const float* __restrict__ partial,  // [B,CPB,N]
    float* __restrict__ out)            // [B,N]
{
    const int idx = blockIdx.x * 256 + threadIdx.x;   // 0..B*N
    const int b = idx >> 6;
    const int n = idx & 63;
    const float* p = partial + (size_t)b * CPB * N_ + n;
    float s = 0.f;
    #pragma unroll
    for (int c = 0; c < CPB; ++c) s += p[c * N_];
    out[idx] = s;
}

extern "C" void kernel_launch(void* const* d_in, const int* in_sizes, int n_in,
                              void* d_out, int out_size, void* d_ws, size_t ws_size,
                              hipStream_t stream) {
    const float* batch   = (const float*)d_in[0];   // [128,4096,2]
    const float* ndp     = (const float*)d_in[1];   // [128,4096]
    const float* centers = (const float*)d_in[2];   // [64,2]
    const float* sharp   = (const float*)d_in[3];   // [64,2]
    float* out     = (float*)d_out;                 // [128,64] fp32
    float* partial = (float*)d_ws;                  // [128,16,64] = 512 KB

    slayer_stage1<<<dim3(B_ * CPB), THREADS, 0, stream>>>(batch, ndp, centers, sharp, partial);
    slayer_stage2<<<dim3((B_ * N_) / 256), 256, 0, stream>>>(partial, out);
}